// Round 7
// baseline (652.167 us; speedup 1.0000x reference)
//
#include <hip/hip_runtime.h>

#define NN 100000
#define NSTEP 5
#define LSTR 264   // ushorts; 528B rows, 16B aligned for ds_read_b128

typedef unsigned short ushort_t;
typedef __attribute__((ext_vector_type(8))) short short8;
typedef __attribute__((ext_vector_type(4))) float floatx4;

__device__ __forceinline__ ushort_t f2bf(float f){
  union { float f; unsigned u; } v; v.f = f;
  unsigned r = v.u + 0x7fffu + ((v.u >> 16) & 1u);
  return (ushort_t)(r >> 16);
}
__device__ __forceinline__ float bf2f(ushort_t s){
  union { unsigned u; float f; } v; v.u = ((unsigned)s) << 16;
  return v.f;
}
__device__ __forceinline__ float sigf(float x){ return 1.0f/(1.0f+__expf(-x)); }

// ================= fused FNN: hfeat = (elu(x@W1+b1))@W2+b2, bf16 out =================
// 1563 blocks x 256 thr (4 waves), 64 rows x 256 cols, 33.8 KB LDS, 4 blocks/CU.
// Weights fragment-major (1KB coalesced wave load); B-frags software-pipelined.
__global__ __launch_bounds__(256, 4) void fnn_fused(const float* __restrict__ x,
    const ushort_t* __restrict__ W1P, const float* __restrict__ b1,
    const ushort_t* __restrict__ W2P, const float* __restrict__ b2,
    ushort_t* __restrict__ hfeat, int M)
{
  __shared__ ushort_t buf[64 * LSTR];
  int tid = threadIdx.x;
  int w = tid >> 6, lane = tid & 63, qd = lane >> 4, r16 = lane & 15;
  int row0 = blockIdx.x * 64;
  int col0 = w * 64;

  // ---- stage x tile (64x256 fp32 -> bf16 LDS) ----
  #pragma unroll
  for (int it = 0; it < 16; it++){
    int idx = it * 256 + tid;
    int r = idx >> 6, c4 = idx & 63;
    int rg = row0 + r; if (rg >= M) rg = M - 1;
    float4 v = *(const float4*)(x + (size_t)rg * 256 + c4 * 4);
    ushort4 pk = make_ushort4(f2bf(v.x), f2bf(v.y), f2bf(v.z), f2bf(v.w));
    *(ushort4*)&buf[r * LSTR + c4 * 4] = pk;
  }
  __syncthreads();

  floatx4 acc[4][4];

  // ---- GEMM1 (B prefetched one kc ahead) ----
  #pragma unroll
  for (int i=0;i<4;i++)
    #pragma unroll
    for (int j=0;j<4;j++) acc[i][j] = (floatx4){0.f,0.f,0.f,0.f};

  {
    const ushort_t* WB = W1P + (size_t)(w*4*8*64 + lane)*8;   // + (j*8 + kc)*512
    short8 bC[4], bN[4];
    #pragma unroll
    for (int j=0;j<4;j++) bC[j] = *(const short8*)(WB + (size_t)(j*8)*512);
    #pragma unroll
    for (int kc = 0; kc < 8; kc++){
      if (kc < 7){
        #pragma unroll
        for (int j=0;j<4;j++) bN[j] = *(const short8*)(WB + (size_t)(j*8 + kc + 1)*512);
      }
      short8 af[4];
      #pragma unroll
      for (int i=0;i<4;i++)
        af[i] = *(const short8*)&buf[(i*16 + r16) * LSTR + kc*32 + qd*8];
      #pragma unroll
      for (int i=0;i<4;i++)
        #pragma unroll
        for (int j=0;j<4;j++)
          acc[i][j] = __builtin_amdgcn_mfma_f32_16x16x32_bf16(af[i], bC[j], acc[i][j], 0, 0, 0);
      #pragma unroll
      for (int j=0;j<4;j++) bC[j] = bN[j];
    }
  }
  __syncthreads();

  // ---- ELU -> t tile in same LDS ----
  #pragma unroll
  for (int i=0;i<4;i++){
    #pragma unroll
    for (int j=0;j<4;j++){
      int col = col0 + j*16 + r16;
      float bb = b1[col];
      #pragma unroll
      for (int rr=0;rr<4;rr++){
        int row = i*16 + qd*4 + rr;
        float v = acc[i][j][rr] + bb;
        v = v > 0.f ? v : (__expf(v) - 1.0f);
        buf[row * LSTR + col] = f2bf(v);
      }
    }
  }
  __syncthreads();

  // ---- GEMM2 ----
  #pragma unroll
  for (int i=0;i<4;i++)
    #pragma unroll
    for (int j=0;j<4;j++) acc[i][j] = (floatx4){0.f,0.f,0.f,0.f};

  {
    const ushort_t* WB = W2P + (size_t)(w*4*8*64 + lane)*8;
    short8 bC[4], bN[4];
    #pragma unroll
    for (int j=0;j<4;j++) bC[j] = *(const short8*)(WB + (size_t)(j*8)*512);
    #pragma unroll
    for (int kc = 0; kc < 8; kc++){
      if (kc < 7){
        #pragma unroll
        for (int j=0;j<4;j++) bN[j] = *(const short8*)(WB + (size_t)(j*8 + kc + 1)*512);
      }
      short8 af[4];
      #pragma unroll
      for (int i=0;i<4;i++)
        af[i] = *(const short8*)&buf[(i*16 + r16) * LSTR + kc*32 + qd*8];
      #pragma unroll
      for (int i=0;i<4;i++)
        #pragma unroll
        for (int j=0;j<4;j++)
          acc[i][j] = __builtin_amdgcn_mfma_f32_16x16x32_bf16(af[i], bC[j], acc[i][j], 0, 0, 0);
      #pragma unroll
      for (int j=0;j<4;j++) bC[j] = bN[j];
    }
  }

  #pragma unroll
  for (int i=0;i<4;i++){
    #pragma unroll
    for (int j=0;j<4;j++){
      int col = col0 + j*16 + r16;
      float bb = b2[col];
      #pragma unroll
      for (int rr=0;rr<4;rr++){
        int row = row0 + i*16 + qd*4 + rr;
        if (row < M) hfeat[(size_t)row * 256 + col] = f2bf(acc[i][j][rr] + bb);
      }
    }
  }
}

// ================= LSTM layer: gates GEMM (K-split x8 waves) + fused cell =================
// 128 blocks x 512 thr (1024 waves). Block = (16 rows, 16 h-cols) x 4 gates.
// L0 variant: A columns 256..511 (the attention readout r) computed on the fly from r/z slices.
__global__ __launch_bounds__(512) void lstm_layer(const ushort_t* __restrict__ A, int lda,
    const ushort_t* __restrict__ WcP, const float* __restrict__ bcp, int KC,
    float* __restrict__ c, ushort_t* __restrict__ dstA, int sA,
    ushort_t* __restrict__ dstB, int sB, float* __restrict__ qdst,
    const float* __restrict__ rsrc, const float* __restrict__ zsrc)
{
  __shared__ float sbuf[7][4][256];
  int tid = threadIdx.x, w = tid >> 6, lane = tid & 63, qd = lane >> 4, r16 = lane & 15;
  int m0 = (blockIdx.x & 7) * 16, nt = blockIdx.x >> 3;
  int kcq = KC >> 3;                       // chunks/wave: 3 (K=768) or 2 (K=512)
  int kc0 = w * kcq;

  float zinv = 0.f;
  if (rsrc) zinv = 1.0f / (zsrc[m0 + r16] + 1e-16f);

  floatx4 acc[4];
  #pragma unroll
  for (int g=0; g<4; g++) acc[g] = (floatx4){0.f,0.f,0.f,0.f};

  const ushort_t* Ar = A + (size_t)(m0 + r16) * lda + qd * 8;
  for (int kc = kc0; kc < kc0 + kcq; kc++){
    short8 av;
    if (rsrc && kc >= 8 && kc < 16){
      const float* rp = rsrc + (m0 + r16)*256 + (kc - 8)*32 + qd*8;
      float4 v0 = *(const float4*)rp;
      float4 v1 = *(const float4*)(rp + 4);
      short8 t;
      t[0]=(short)f2bf(v0.x*zinv); t[1]=(short)f2bf(v0.y*zinv);
      t[2]=(short)f2bf(v0.z*zinv); t[3]=(short)f2bf(v0.w*zinv);
      t[4]=(short)f2bf(v1.x*zinv); t[5]=(short)f2bf(v1.y*zinv);
      t[6]=(short)f2bf(v1.z*zinv); t[7]=(short)f2bf(v1.w*zinv);
      av = t;
    } else {
      av = *(const short8*)(Ar + kc*32);
    }
    #pragma unroll
    for (int g = 0; g < 4; g++){
      short8 bv = *(const short8*)(WcP + (size_t)((((g*16 + nt)*KC) + kc)*64 + lane)*8);
      acc[g] = __builtin_amdgcn_mfma_f32_16x16x32_bf16(av, bv, acc[g], 0, 0, 0);
    }
  }
  if (w){
    #pragma unroll
    for (int g=0; g<4; g++) *(floatx4*)&sbuf[w-1][g][lane*4] = acc[g];
  }
  __syncthreads();
  if (w == 0){
    #pragma unroll
    for (int g=0; g<4; g++)
      #pragma unroll
      for (int t=0; t<7; t++){
        floatx4 p = *(floatx4*)&sbuf[t][g][lane*4];
        acc[g] = acc[g] + p;
      }
    int h = nt*16 + r16;
    float bci = bcp[h], bcf = bcp[256+h], bcg = bcp[512+h], bco = bcp[768+h];
    #pragma unroll
    for (int rr=0; rr<4; rr++){
      int row = m0 + qd*4 + rr;
      float gi = acc[0][rr] + bci;
      float gf = acc[1][rr] + bcf;
      float gg = acc[2][rr] + bcg;
      float go = acc[3][rr] + bco;
      float cp = c[row*256 + h];
      float cn = sigf(gf)*cp + sigf(gi)*tanhf(gg);
      float hn = sigf(go)*tanhf(cn);
      c[row*256 + h] = cn;
      ushort_t hb = f2bf(hn);
      dstA[row*sA + h] = hb;
      dstB[row*sB + h] = hb;
      if (qdst) qdst[row*512 + h] = hn;
    }
  }
}

// ================= one-pass attention: S[b] += exp(e_n)*h_n, Z[b] += exp(e_n) =================
// 2048 blocks x 256 thr = 8192 waves (32/CU). Wave = 13 contiguous sorted nodes.
// No max-subtract (|e| small, fp32 exp safe). Normalization deferred to consumers.
__global__ __launch_bounds__(256) void attn_onepass(const ushort_t* __restrict__ hfeat,
    const int* __restrict__ bidx, const float* __restrict__ q_star,
    float* __restrict__ r_acc, float* __restrict__ z_acc)
{
  const int CH = (NN + 8191) / 8192;       // 13
  int gw = blockIdx.x*4 + (threadIdx.x >> 6);
  int lane = threadIdx.x & 63;
  int n0 = gw * CH;
  if (n0 >= NN) return;
  int nend = n0 + CH; if (nend > NN) nend = NN;

  int bcur = bidx[n0];
  float4 q = *(const float4*)(q_star + (size_t)bcur*512 + lane*4);
  float S0=0.f, S1=0.f, S2=0.f, S3=0.f, Z=0.f;

  ushort4 h = *(const ushort4*)(hfeat + (size_t)n0*256 + lane*4);
  for (int n = n0; n < nend; n++){
    ushort4 hn;
    int bn = bcur;
    if (n + 1 < nend){
      hn = *(const ushort4*)(hfeat + (size_t)(n+1)*256 + lane*4);
      bn = bidx[n+1];
    }
    float f0 = bf2f(h.x), f1 = bf2f(h.y), f2 = bf2f(h.z), f3 = bf2f(h.w);
    float d = f0*q.x + f1*q.y + f2*q.z + f3*q.w;
    #pragma unroll
    for (int off = 32; off; off >>= 1) d += __shfl_xor(d, off);
    float wgt = __expf(d);
    Z += wgt;
    S0 += wgt*f0; S1 += wgt*f1; S2 += wgt*f2; S3 += wgt*f3;
    if (bn != bcur){
      float* rp = r_acc + bcur*256 + lane*4;
      atomicAdd(rp+0, S0); atomicAdd(rp+1, S1);
      atomicAdd(rp+2, S2); atomicAdd(rp+3, S3);
      if (lane == 0) atomicAdd(&z_acc[bcur], Z);
      S0=S1=S2=S3=Z=0.f;
      bcur = bn;
      q = *(const float4*)(q_star + (size_t)bcur*512 + lane*4);
    }
    h = hn;
  }
  float* rp = r_acc + bcur*256 + lane*4;
  atomicAdd(rp+0, S0); atomicAdd(rp+1, S1);
  atomicAdd(rp+2, S2); atomicAdd(rp+3, S3);
  if (lane == 0) atomicAdd(&z_acc[bcur], Z);
}

// ================= final: out(128,128) = [q | r5/z5] @ outW + outb =================
__global__ __launch_bounds__(256) void final_k(const float* __restrict__ q_star,
    const float* __restrict__ r5, const float* __restrict__ z5,
    const float* __restrict__ outW, const float* __restrict__ outb, float* __restrict__ out)
{
  __shared__ float qs[512];
  int b = blockIdx.x, f = threadIdx.x;
  qs[f] = q_star[b*512 + f];
  qs[256 + f] = r5[b*256 + f] / (z5[b] + 1e-16f);
  __syncthreads();
  if (f < 128){
    float acc = outb[f];
    for (int k = 0; k < 512; k++) acc += qs[k] * outW[k*128 + f];
    out[b*128 + f] = acc;
  }
}

// ================= prep: fragment-major packing (coalesced READS) + init =================
// Packed layout: P[((T*KC + kc)*64 + qd*16 + r16)*8 + j] = BT[T*16 + r16][kc*32 + qd*8 + j]
__global__ void prep_all(const float* __restrict__ W1, const float* __restrict__ W2,
    const float* __restrict__ Wih0, const float* __restrict__ Whh0,
    const float* __restrict__ Wih1, const float* __restrict__ Whh1,
    const float* __restrict__ Wih2, const float* __restrict__ Whh2,
    const float* __restrict__ bih0, const float* __restrict__ bhh0,
    const float* __restrict__ bih1, const float* __restrict__ bhh1,
    const float* __restrict__ bih2, const float* __restrict__ bhh2,
    const int* __restrict__ bidx,
    ushort_t* __restrict__ W1P, ushort_t* __restrict__ W2P,
    ushort_t* __restrict__ Wc0P, ushort_t* __restrict__ Wc1P, ushort_t* __restrict__ Wc2P,
    float* __restrict__ c, ushort_t* __restrict__ xc, float* __restrict__ q_star,
    float* __restrict__ bc, int* __restrict__ seg,
    float* __restrict__ r_sl, float* __restrict__ z_sl)
{
  int i = blockIdx.x*256 + threadIdx.x;
  // --- W1/W2 (K=256, KC=8): read linear W[k*256+n] ---
  if (i < 131072){
    const float* W = (i < 65536) ? W1 : W2;
    ushort_t* P = (i < 65536) ? W1P : W2P;
    int s = i & 65535;
    int k = s >> 8, n = s & 255;
    int T = n >> 4, r16 = n & 15, kc = k >> 5, qd = (k >> 3) & 3, j = k & 7;
    P[((T*8 + kc)*64 + qd*16 + r16)*8 + j] = f2bf(W[s]);
    return;
  }
  i -= 131072;
  // --- Wih0 (1024x512), KC=24, kc = k>>5 ---
  if (i < 524288){
    int R = i >> 9, k = i & 511;
    int T = (R >> 8)*16 + ((R >> 4) & 15), r16 = R & 15;
    int kc = k >> 5, qd = (k >> 3) & 3, j = k & 7;
    Wc0P[((T*24 + kc)*64 + qd*16 + r16)*8 + j] = f2bf(Wih0[i]);
    return;
  }
  i -= 524288;
  // --- Whh0 (1024x256), kc = 16 + (k>>5) ---
  if (i < 262144){
    int R = i >> 8, k = i & 255;
    int T = (R >> 8)*16 + ((R >> 4) & 15), r16 = R & 15;
    int kc = 16 + (k >> 5), qd = (k >> 3) & 3, j = k & 7;
    Wc0P[((T*24 + kc)*64 + qd*16 + r16)*8 + j] = f2bf(Whh0[i]);
    return;
  }
  i -= 262144;
  // --- Wih1 / Whh1 / Wih2 / Whh2 (1024x256 each), KC=16 ---
  if (i < 1048576){
    int which = i >> 18;                   // 0:Wih1 1:Whh1 2:Wih2 3:Whh2
    const float* W = (which == 0) ? Wih1 : (which == 1) ? Whh1 : (which == 2) ? Wih2 : Whh2;
    ushort_t* P = (which < 2) ? Wc1P : Wc2P;
    int s = i & 262143;
    int R = s >> 8, k = s & 255;
    int T = (R >> 8)*16 + ((R >> 4) & 15), r16 = R & 15;
    int kc = ((which & 1) ? 8 : 0) + (k >> 5), qd = (k >> 3) & 3, j = k & 7;
    P[((T*16 + kc)*64 + qd*16 + r16)*8 + j] = f2bf(W[s]);
    return;
  }
  i -= 1048576;
  if (i < 98304) { c[i] = 0.f; return; }
  i -= 98304;
  if (i < 229376) { xc[i] = 0; return; }
  i -= 229376;
  if (i < 65536) { q_star[i] = 0.f; return; }
  i -= 65536;
  if (i < 3072) {
    int l = i >> 10, g = i & 1023;
    const float* bi = (l == 0) ? bih0 : ((l == 1) ? bih1 : bih2);
    const float* bh = (l == 0) ? bhh0 : ((l == 1) ? bhh1 : bhh2);
    bc[i] = bi[g] + bh[g];
    return;
  }
  i -= 3072;
  if (i < 129) {
    int lo = 0, hi = NN;
    while (lo < hi){ int mid = (lo + hi) >> 1; if (bidx[mid] < i) lo = mid + 1; else hi = mid; }
    seg[i] = lo;
    return;
  }
  i -= 129;
  if (i < 196608) { r_sl[i] = 0.f; return; }
  i -= 196608;
  if (i < 768) z_sl[i] = 0.f;
}

extern "C" void kernel_launch(void* const* d_in, const int* in_sizes, int n_in,
                              void* d_out, int out_size, void* d_ws, size_t ws_size,
                              hipStream_t stream)
{
  const float* x    = (const float*)d_in[0];
  const int*   bidx = (const int*)  d_in[1];
  const float* W1   = (const float*)d_in[2];
  const float* b1   = (const float*)d_in[3];
  const float* W2   = (const float*)d_in[4];
  const float* b2   = (const float*)d_in[5];
  const float* Wih0 = (const float*)d_in[6];
  const float* Whh0 = (const float*)d_in[7];
  const float* bih0 = (const float*)d_in[8];
  const float* bhh0 = (const float*)d_in[9];
  const float* Wih1 = (const float*)d_in[10];
  const float* Whh1 = (const float*)d_in[11];
  const float* bih1 = (const float*)d_in[12];
  const float* bhh1 = (const float*)d_in[13];
  const float* Wih2 = (const float*)d_in[14];
  const float* Whh2 = (const float*)d_in[15];
  const float* bih2 = (const float*)d_in[16];
  const float* bhh2 = (const float*)d_in[17];
  const float* outW = (const float*)d_in[18];
  const float* outb = (const float*)d_in[19];

  char* p = (char*)d_ws;
  auto alloc = [&](size_t bytes)->char*{ char* r = p; p += (bytes + 255) & ~(size_t)255; return r; };
  ushort_t* hfeat  = (ushort_t*)alloc((size_t)NN*256*2);   // bf16 node features
  ushort_t* W1P    = (ushort_t*)alloc(65536*2);
  ushort_t* W2P    = (ushort_t*)alloc(65536*2);
  ushort_t* Wc0P   = (ushort_t*)alloc(786432*2);
  ushort_t* Wc1P   = (ushort_t*)alloc(524288*2);
  ushort_t* Wc2P   = (ushort_t*)alloc(524288*2);
  float*    bc     = (float*)   alloc(3072*4);
  float*    c_all  = (float*)   alloc(98304*4);
  ushort_t* xc     = (ushort_t*)alloc(229376*2);           // xc0(128x768)|xc1(128x512)|xc2(128x512)
  float*    q_star = (float*)   alloc(65536*4);            // (128,512); only q half written/used
  float*    r_sl   = (float*)   alloc(196608*4);           // 6 slices of (128,256)
  float*    z_sl   = (float*)   alloc(768*4);              // 6 slices of (128)
  int*      seg    = (int*)     alloc(129*4);

  ushort_t* xc0 = xc;
  ushort_t* xc1 = xc + 98304;
  ushort_t* xc2 = xc + 163840;
  float* c0 = c_all, *c1 = c_all + 32768, *c2 = c_all + 65536;
  float* bc0 = bc, *bc1 = bc + 1024, *bc2 = bc + 2048;

  prep_all<<<10000, 256, 0, stream>>>(W1, W2, Wih0, Whh0, Wih1, Whh1, Wih2, Whh2,
                                      bih0, bhh0, bih1, bhh1, bih2, bhh2, bidx,
                                      W1P, W2P, Wc0P, Wc1P, Wc2P,
                                      c_all, xc, q_star, bc, seg, r_sl, z_sl);

  fnn_fused<<<1563, 256, 0, stream>>>(x, W1P, b1, W2P, b2, hfeat, NN);

  for (int s = 0; s < NSTEP; s++){
    float* r_in  = r_sl + s*32768;       float* z_in  = z_sl + s*128;
    float* r_out = r_sl + (s+1)*32768;   float* z_out = z_sl + (s+1)*128;
    // layer 0: in = [q | r(from slices) | h0_prev] (K=768, KC=24)
    lstm_layer<<<128, 512, 0, stream>>>(xc0, 768, Wc0P, bc0, 24, c0,
                                        xc0 + 512, 768, xc1, 512, nullptr, r_in, z_in);
    // layer 1: in = [h0 | h1_prev] (K=512, KC=16)
    lstm_layer<<<128, 512, 0, stream>>>(xc1, 512, Wc1P, bc1, 16, c1,
                                        xc1 + 256, 512, xc2, 512, nullptr, nullptr, nullptr);
    // layer 2: in = [h1 | h2_prev]; h2 = q -> xc0[:, :256] bf16 + q_star fp32
    lstm_layer<<<128, 512, 0, stream>>>(xc2, 512, Wc2P, bc2, 16, c2,
                                        xc2 + 256, 512, xc0, 768, q_star, nullptr, nullptr);
    // one-pass attention into slice s+1
    attn_onepass<<<2048, 256, 0, stream>>>(hfeat, bidx, q_star, r_out, z_out);
  }

  final_k<<<128, 256, 0, stream>>>(q_star, r_sl + 5*32768, z_sl + 5*128,
                                   outW, outb, (float*)d_out);
}

// Round 8
// 556.734 us; speedup vs baseline: 1.1714x; 1.1714x over previous
//
#include <hip/hip_runtime.h>

#define NN 100000
#define NSTEP 5
#define LSTR 264   // ushorts; 528B rows, 16B aligned for ds_read_b128

typedef unsigned short ushort_t;
typedef __attribute__((ext_vector_type(8))) short short8;
typedef __attribute__((ext_vector_type(4))) float floatx4;

__device__ __forceinline__ ushort_t f2bf(float f){
  union { float f; unsigned u; } v; v.f = f;
  unsigned r = v.u + 0x7fffu + ((v.u >> 16) & 1u);
  return (ushort_t)(r >> 16);
}
__device__ __forceinline__ float bf2f(ushort_t s){
  union { unsigned u; float f; } v; v.u = ((unsigned)s) << 16;
  return v.f;
}
__device__ __forceinline__ float sigf(float x){ return 1.0f/(1.0f+__expf(-x)); }

// ================= fused FNN: hfeat = (elu(x@W1+b1))@W2+b2, bf16 out =================
// 1563 blocks x 256 thr (4 waves), 64 rows x 256 cols, 33.8 KB LDS, 4 blocks/CU.
// Staging uses 8-deep explicit load pipeline (MLP) so L3/HBM latency overlaps.
__global__ __launch_bounds__(256, 4) void fnn_fused(const float* __restrict__ x,
    const ushort_t* __restrict__ W1P, const float* __restrict__ b1,
    const ushort_t* __restrict__ W2P, const float* __restrict__ b2,
    ushort_t* __restrict__ hfeat, int M)
{
  __shared__ ushort_t buf[64 * LSTR];
  int tid = threadIdx.x;
  int w = tid >> 6, lane = tid & 63, qd = lane >> 4, r16 = lane & 15;
  int row0 = blockIdx.x * 64;
  int col0 = w * 64;

  // ---- stage x tile (64x256 fp32 -> bf16 LDS), 8 loads in flight ----
  #pragma unroll
  for (int g = 0; g < 2; g++){
    float4 v[8];
    #pragma unroll
    for (int u = 0; u < 8; u++){
      int idx = (g*8 + u) * 256 + tid;
      int r = idx >> 6, c4 = idx & 63;
      int rg = row0 + r; if (rg >= M) rg = M - 1;
      v[u] = *(const float4*)(x + (size_t)rg * 256 + c4 * 4);
    }
    #pragma unroll
    for (int u = 0; u < 8; u++){
      int idx = (g*8 + u) * 256 + tid;
      int r = idx >> 6, c4 = idx & 63;
      ushort4 pk = make_ushort4(f2bf(v[u].x), f2bf(v[u].y), f2bf(v[u].z), f2bf(v[u].w));
      *(ushort4*)&buf[r * LSTR + c4 * 4] = pk;
    }
  }
  __syncthreads();

  floatx4 acc[4][4];

  // ---- GEMM1 (B prefetched one kc ahead) ----
  #pragma unroll
  for (int i=0;i<4;i++)
    #pragma unroll
    for (int j=0;j<4;j++) acc[i][j] = (floatx4){0.f,0.f,0.f,0.f};

  {
    const ushort_t* WB = W1P + (size_t)(w*4*8*64 + lane)*8;   // + (j*8 + kc)*512
    short8 bC[4], bN[4];
    #pragma unroll
    for (int j=0;j<4;j++) bC[j] = *(const short8*)(WB + (size_t)(j*8)*512);
    #pragma unroll
    for (int kc = 0; kc < 8; kc++){
      if (kc < 7){
        #pragma unroll
        for (int j=0;j<4;j++) bN[j] = *(const short8*)(WB + (size_t)(j*8 + kc + 1)*512);
      }
      short8 af[4];
      #pragma unroll
      for (int i=0;i<4;i++)
        af[i] = *(const short8*)&buf[(i*16 + r16) * LSTR + kc*32 + qd*8];
      #pragma unroll
      for (int i=0;i<4;i++)
        #pragma unroll
        for (int j=0;j<4;j++)
          acc[i][j] = __builtin_amdgcn_mfma_f32_16x16x32_bf16(af[i], bC[j], acc[i][j], 0, 0, 0);
      #pragma unroll
      for (int j=0;j<4;j++) bC[j] = bN[j];
    }
  }
  __syncthreads();

  // ---- ELU -> t tile in same LDS ----
  #pragma unroll
  for (int i=0;i<4;i++){
    #pragma unroll
    for (int j=0;j<4;j++){
      int col = col0 + j*16 + r16;
      float bb = b1[col];
      #pragma unroll
      for (int rr=0;rr<4;rr++){
        int row = i*16 + qd*4 + rr;
        float v = acc[i][j][rr] + bb;
        v = v > 0.f ? v : (__expf(v) - 1.0f);
        buf[row * LSTR + col] = f2bf(v);
      }
    }
  }
  __syncthreads();

  // ---- GEMM2 ----
  #pragma unroll
  for (int i=0;i<4;i++)
    #pragma unroll
    for (int j=0;j<4;j++) acc[i][j] = (floatx4){0.f,0.f,0.f,0.f};

  {
    const ushort_t* WB = W2P + (size_t)(w*4*8*64 + lane)*8;
    short8 bC[4], bN[4];
    #pragma unroll
    for (int j=0;j<4;j++) bC[j] = *(const short8*)(WB + (size_t)(j*8)*512);
    #pragma unroll
    for (int kc = 0; kc < 8; kc++){
      if (kc < 7){
        #pragma unroll
        for (int j=0;j<4;j++) bN[j] = *(const short8*)(WB + (size_t)(j*8 + kc + 1)*512);
      }
      short8 af[4];
      #pragma unroll
      for (int i=0;i<4;i++)
        af[i] = *(const short8*)&buf[(i*16 + r16) * LSTR + kc*32 + qd*8];
      #pragma unroll
      for (int i=0;i<4;i++)
        #pragma unroll
        for (int j=0;j<4;j++)
          acc[i][j] = __builtin_amdgcn_mfma_f32_16x16x32_bf16(af[i], bC[j], acc[i][j], 0, 0, 0);
      #pragma unroll
      for (int j=0;j<4;j++) bC[j] = bN[j];
    }
  }

  #pragma unroll
  for (int i=0;i<4;i++){
    #pragma unroll
    for (int j=0;j<4;j++){
      int col = col0 + j*16 + r16;
      float bb = b2[col];
      #pragma unroll
      for (int rr=0;rr<4;rr++){
        int row = row0 + i*16 + qd*4 + rr;
        if (row < M) hfeat[(size_t)row * 256 + col] = f2bf(acc[i][j][rr] + bb);
      }
    }
  }
}

// ================= LSTM layer: gates GEMM (K-split x4 waves) + fused cell =================
// 128 blocks x 256 thr. Block = (16 rows, 16 h-cols) x 4 gates. Weights fragment-major.
// L0: A columns 256..511 (attention readout r) computed on the fly from r/z slices.
__global__ __launch_bounds__(256) void lstm_layer(const ushort_t* __restrict__ A, int lda,
    const ushort_t* __restrict__ WcP, const float* __restrict__ bcp, int KC,
    float* __restrict__ c, ushort_t* __restrict__ dstA, int sA,
    ushort_t* __restrict__ dstB, int sB, float* __restrict__ qdst,
    const float* __restrict__ rsrc, const float* __restrict__ zsrc)
{
  __shared__ float sbuf[3][4][256];
  int tid = threadIdx.x, w = tid >> 6, lane = tid & 63, qd = lane >> 4, r16 = lane & 15;
  int m0 = (blockIdx.x & 7) * 16, nt = blockIdx.x >> 3;
  int kcq = KC >> 2;                       // chunks/wave: 6 (K=768) or 4 (K=512)
  int kc0 = w * kcq;

  float zinv = 0.f;
  if (rsrc) zinv = 1.0f / (zsrc[m0 + r16] + 1e-16f);

  floatx4 acc[4];
  #pragma unroll
  for (int g=0; g<4; g++) acc[g] = (floatx4){0.f,0.f,0.f,0.f};

  const ushort_t* Ar = A + (size_t)(m0 + r16) * lda + qd * 8;
  for (int kc = kc0; kc < kc0 + kcq; kc++){
    short8 av;
    if (rsrc && kc >= 8 && kc < 16){
      const float* rp = rsrc + (m0 + r16)*256 + (kc - 8)*32 + qd*8;
      float4 v0 = *(const float4*)rp;
      float4 v1 = *(const float4*)(rp + 4);
      short8 t;
      t[0]=(short)f2bf(v0.x*zinv); t[1]=(short)f2bf(v0.y*zinv);
      t[2]=(short)f2bf(v0.z*zinv); t[3]=(short)f2bf(v0.w*zinv);
      t[4]=(short)f2bf(v1.x*zinv); t[5]=(short)f2bf(v1.y*zinv);
      t[6]=(short)f2bf(v1.z*zinv); t[7]=(short)f2bf(v1.w*zinv);
      av = t;
    } else {
      av = *(const short8*)(Ar + kc*32);
    }
    #pragma unroll
    for (int g = 0; g < 4; g++){
      short8 bv = *(const short8*)(WcP + (size_t)((((g*16 + nt)*KC) + kc)*64 + lane)*8);
      acc[g] = __builtin_amdgcn_mfma_f32_16x16x32_bf16(av, bv, acc[g], 0, 0, 0);
    }
  }
  if (w){
    #pragma unroll
    for (int g=0; g<4; g++) *(floatx4*)&sbuf[w-1][g][lane*4] = acc[g];
  }
  __syncthreads();
  if (w == 0){
    #pragma unroll
    for (int g=0; g<4; g++)
      #pragma unroll
      for (int t=0; t<3; t++){
        floatx4 p = *(floatx4*)&sbuf[t][g][lane*4];
        acc[g] = acc[g] + p;
      }
    int h = nt*16 + r16;
    float bci = bcp[h], bcf = bcp[256+h], bcg = bcp[512+h], bco = bcp[768+h];
    #pragma unroll
    for (int rr=0; rr<4; rr++){
      int row = m0 + qd*4 + rr;
      float gi = acc[0][rr] + bci;
      float gf = acc[1][rr] + bcf;
      float gg = acc[2][rr] + bcg;
      float go = acc[3][rr] + bco;
      float cp = c[row*256 + h];
      float cn = sigf(gf)*cp + sigf(gi)*tanhf(gg);
      float hn = sigf(go)*tanhf(cn);
      c[row*256 + h] = cn;
      ushort_t hb = f2bf(hn);
      dstA[row*sA + h] = hb;
      dstB[row*sB + h] = hb;
      if (qdst) qdst[row*512 + h] = hn;
    }
  }
}

// ================= one-pass attention: S[b] += exp(e_n)*h_n, Z[b] += exp(e_n) =================
// 512 blocks x 256 thr = 2048 waves, wave = 49 contiguous sorted nodes, rows prefetched
// 2 deep to hide L3 latency. No max-subtract (|e| small). Normalization in consumers.
__global__ __launch_bounds__(256) void attn_onepass(const ushort_t* __restrict__ hfeat,
    const int* __restrict__ bidx, const float* __restrict__ q_star,
    float* __restrict__ r_acc, float* __restrict__ z_acc)
{
  const int CH = (NN + 2047) / 2048;       // 49
  int gw = blockIdx.x*4 + (threadIdx.x >> 6);
  int lane = threadIdx.x & 63;
  int n0 = gw * CH;
  if (n0 >= NN) return;
  int nend = n0 + CH; if (nend > NN) nend = NN;

  int bcur = bidx[n0];
  float4 q = *(const float4*)(q_star + (size_t)bcur*512 + lane*4);
  float S0=0.f, S1=0.f, S2=0.f, S3=0.f, Z=0.f;

  ushort4 hA = *(const ushort4*)(hfeat + (size_t)n0*256 + lane*4);
  ushort4 hB = (n0 + 1 < nend) ? *(const ushort4*)(hfeat + (size_t)(n0+1)*256 + lane*4) : hA;
  for (int n = n0; n < nend; n++){
    ushort4 hC = hB;
    if (n + 2 < nend) hC = *(const ushort4*)(hfeat + (size_t)(n+2)*256 + lane*4);
    int bn = (n + 1 < nend) ? bidx[n+1] : bcur;
    float f0 = bf2f(hA.x), f1 = bf2f(hA.y), f2 = bf2f(hA.z), f3 = bf2f(hA.w);
    float d = f0*q.x + f1*q.y + f2*q.z + f3*q.w;
    #pragma unroll
    for (int off = 32; off; off >>= 1) d += __shfl_xor(d, off);
    float wgt = __expf(d);
    Z += wgt;
    S0 += wgt*f0; S1 += wgt*f1; S2 += wgt*f2; S3 += wgt*f3;
    if (bn != bcur){
      float* rp = r_acc + bcur*256 + lane*4;
      atomicAdd(rp+0, S0); atomicAdd(rp+1, S1);
      atomicAdd(rp+2, S2); atomicAdd(rp+3, S3);
      if (lane == 0) atomicAdd(&z_acc[bcur], Z);
      S0=S1=S2=S3=Z=0.f;
      bcur = bn;
      q = *(const float4*)(q_star + (size_t)bcur*512 + lane*4);
    }
    hA = hB; hB = hC;
  }
  float* rp = r_acc + bcur*256 + lane*4;
  atomicAdd(rp+0, S0); atomicAdd(rp+1, S1);
  atomicAdd(rp+2, S2); atomicAdd(rp+3, S3);
  if (lane == 0) atomicAdd(&z_acc[bcur], Z);
}

// ================= final: out(128,128) = [q | r5/z5] @ outW + outb =================
__global__ __launch_bounds__(256) void final_k(const float* __restrict__ q_star,
    const float* __restrict__ r5, const float* __restrict__ z5,
    const float* __restrict__ outW, const float* __restrict__ outb, float* __restrict__ out)
{
  __shared__ float qs[512];
  int b = blockIdx.x, f = threadIdx.x;
  qs[f] = q_star[b*512 + f];
  qs[256 + f] = r5[b*256 + f] / (z5[b] + 1e-16f);
  __syncthreads();
  if (f < 128){
    float acc = outb[f];
    for (int k = 0; k < 512; k++) acc += qs[k] * outW[k*128 + f];
    out[b*128 + f] = acc;
  }
}

// ================= prep: fragment-major packing (coalesced READS) + init =================
// Packed layout: P[((T*KC + kc)*64 + qd*16 + r16)*8 + j] = BT[T*16 + r16][kc*32 + qd*8 + j]
__global__ void prep_all(const float* __restrict__ W1, const float* __restrict__ W2,
    const float* __restrict__ Wih0, const float* __restrict__ Whh0,
    const float* __restrict__ Wih1, const float* __restrict__ Whh1,
    const float* __restrict__ Wih2, const float* __restrict__ Whh2,
    const float* __restrict__ bih0, const float* __restrict__ bhh0,
    const float* __restrict__ bih1, const float* __restrict__ bhh1,
    const float* __restrict__ bih2, const float* __restrict__ bhh2,
    const int* __restrict__ bidx,
    ushort_t* __restrict__ W1P, ushort_t* __restrict__ W2P,
    ushort_t* __restrict__ Wc0P, ushort_t* __restrict__ Wc1P, ushort_t* __restrict__ Wc2P,
    float* __restrict__ c, ushort_t* __restrict__ xc, float* __restrict__ q_star,
    float* __restrict__ bc, int* __restrict__ seg,
    float* __restrict__ r_sl, float* __restrict__ z_sl)
{
  int i = blockIdx.x*256 + threadIdx.x;
  // --- W1/W2 (K=256, KC=8): read linear W[k*256+n] ---
  if (i < 131072){
    const float* W = (i < 65536) ? W1 : W2;
    ushort_t* P = (i < 65536) ? W1P : W2P;
    int s = i & 65535;
    int k = s >> 8, n = s & 255;
    int T = n >> 4, r16 = n & 15, kc = k >> 5, qd = (k >> 3) & 3, j = k & 7;
    P[((T*8 + kc)*64 + qd*16 + r16)*8 + j] = f2bf(W[s]);
    return;
  }
  i -= 131072;
  // --- Wih0 (1024x512), KC=24, kc = k>>5 ---
  if (i < 524288){
    int R = i >> 9, k = i & 511;
    int T = (R >> 8)*16 + ((R >> 4) & 15), r16 = R & 15;
    int kc = k >> 5, qd = (k >> 3) & 3, j = k & 7;
    Wc0P[((T*24 + kc)*64 + qd*16 + r16)*8 + j] = f2bf(Wih0[i]);
    return;
  }
  i -= 524288;
  // --- Whh0 (1024x256), kc = 16 + (k>>5) ---
  if (i < 262144){
    int R = i >> 8, k = i & 255;
    int T = (R >> 8)*16 + ((R >> 4) & 15), r16 = R & 15;
    int kc = 16 + (k >> 5), qd = (k >> 3) & 3, j = k & 7;
    Wc0P[((T*24 + kc)*64 + qd*16 + r16)*8 + j] = f2bf(Whh0[i]);
    return;
  }
  i -= 262144;
  // --- Wih1 / Whh1 / Wih2 / Whh2 (1024x256 each), KC=16 ---
  if (i < 1048576){
    int which = i >> 18;                   // 0:Wih1 1:Whh1 2:Wih2 3:Whh2
    const float* W = (which == 0) ? Wih1 : (which == 1) ? Whh1 : (which == 2) ? Wih2 : Whh2;
    ushort_t* P = (which < 2) ? Wc1P : Wc2P;
    int s = i & 262143;
    int R = s >> 8, k = s & 255;
    int T = (R >> 8)*16 + ((R >> 4) & 15), r16 = R & 15;
    int kc = ((which & 1) ? 8 : 0) + (k >> 5), qd = (k >> 3) & 3, j = k & 7;
    P[((T*16 + kc)*64 + qd*16 + r16)*8 + j] = f2bf(W[s]);
    return;
  }
  i -= 1048576;
  if (i < 98304) { c[i] = 0.f; return; }
  i -= 98304;
  if (i < 229376) { xc[i] = 0; return; }
  i -= 229376;
  if (i < 65536) { q_star[i] = 0.f; return; }
  i -= 65536;
  if (i < 3072) {
    int l = i >> 10, g = i & 1023;
    const float* bi = (l == 0) ? bih0 : ((l == 1) ? bih1 : bih2);
    const float* bh = (l == 0) ? bhh0 : ((l == 1) ? bhh1 : bhh2);
    bc[i] = bi[g] + bh[g];
    return;
  }
  i -= 3072;
  if (i < 129) {
    int lo = 0, hi = NN;
    while (lo < hi){ int mid = (lo + hi) >> 1; if (bidx[mid] < i) lo = mid + 1; else hi = mid; }
    seg[i] = lo;
    return;
  }
  i -= 129;
  if (i < 196608) { r_sl[i] = 0.f; return; }
  i -= 196608;
  if (i < 768) z_sl[i] = 0.f;
}

extern "C" void kernel_launch(void* const* d_in, const int* in_sizes, int n_in,
                              void* d_out, int out_size, void* d_ws, size_t ws_size,
                              hipStream_t stream)
{
  const float* x    = (const float*)d_in[0];
  const int*   bidx = (const int*)  d_in[1];
  const float* W1   = (const float*)d_in[2];
  const float* b1   = (const float*)d_in[3];
  const float* W2   = (const float*)d_in[4];
  const float* b2   = (const float*)d_in[5];
  const float* Wih0 = (const float*)d_in[6];
  const float* Whh0 = (const float*)d_in[7];
  const float* bih0 = (const float*)d_in[8];
  const float* bhh0 = (const float*)d_in[9];
  const float* Wih1 = (const float*)d_in[10];
  const float* Whh1 = (const float*)d_in[11];
  const float* bih1 = (const float*)d_in[12];
  const float* bhh1 = (const float*)d_in[13];
  const float* Wih2 = (const float*)d_in[14];
  const float* Whh2 = (const float*)d_in[15];
  const float* bih2 = (const float*)d_in[16];
  const float* bhh2 = (const float*)d_in[17];
  const float* outW = (const float*)d_in[18];
  const float* outb = (const float*)d_in[19];

  char* p = (char*)d_ws;
  auto alloc = [&](size_t bytes)->char*{ char* r = p; p += (bytes + 255) & ~(size_t)255; return r; };
  ushort_t* hfeat  = (ushort_t*)alloc((size_t)NN*256*2);   // bf16 node features
  ushort_t* W1P    = (ushort_t*)alloc(65536*2);
  ushort_t* W2P    = (ushort_t*)alloc(65536*2);
  ushort_t* Wc0P   = (ushort_t*)alloc(786432*2);
  ushort_t* Wc1P   = (ushort_t*)alloc(524288*2);
  ushort_t* Wc2P   = (ushort_t*)alloc(524288*2);
  float*    bc     = (float*)   alloc(3072*4);
  float*    c_all  = (float*)   alloc(98304*4);
  ushort_t* xc     = (ushort_t*)alloc(229376*2);           // xc0(128x768)|xc1(128x512)|xc2(128x512)
  float*    q_star = (float*)   alloc(65536*4);            // (128,512); only q half written/used
  float*    r_sl   = (float*)   alloc(196608*4);           // 6 slices of (128,256)
  float*    z_sl   = (float*)   alloc(768*4);              // 6 slices of (128)
  int*      seg    = (int*)     alloc(129*4);

  ushort_t* xc0 = xc;
  ushort_t* xc1 = xc + 98304;
  ushort_t* xc2 = xc + 163840;
  float* c0 = c_all, *c1 = c_all + 32768, *c2 = c_all + 65536;
  float* bc0 = bc, *bc1 = bc + 1024, *bc2 = bc + 2048;

  prep_all<<<10000, 256, 0, stream>>>(W1, W2, Wih0, Whh0, Wih1, Whh1, Wih2, Whh2,
                                      bih0, bhh0, bih1, bhh1, bih2, bhh2, bidx,
                                      W1P, W2P, Wc0P, Wc1P, Wc2P,
                                      c_all, xc, q_star, bc, seg, r_sl, z_sl);

  fnn_fused<<<1563, 256, 0, stream>>>(x, W1P, b1, W2P, b2, hfeat, NN);

  for (int s = 0; s < NSTEP; s++){
    float* r_in  = r_sl + s*32768;       float* z_in  = z_sl + s*128;
    float* r_out = r_sl + (s+1)*32768;   float* z_out = z_sl + (s+1)*128;
    // layer 0: in = [q | r(from slices) | h0_prev] (K=768, KC=24)
    lstm_layer<<<128, 256, 0, stream>>>(xc0, 768, Wc0P, bc0, 24, c0,
                                        xc0 + 512, 768, xc1, 512, nullptr, r_in, z_in);
    // layer 1: in = [h0 | h1_prev] (K=512, KC=16)
    lstm_layer<<<128, 256, 0, stream>>>(xc1, 512, Wc1P, bc1, 16, c1,
                                        xc1 + 256, 512, xc2, 512, nullptr, nullptr, nullptr);
    // layer 2: in = [h1 | h2_prev]; h2 = q -> xc0[:, :256] bf16 + q_star fp32
    lstm_layer<<<128, 256, 0, stream>>>(xc2, 512, Wc2P, bc2, 16, c2,
                                        xc2 + 256, 512, xc0, 768, q_star, nullptr, nullptr);
    // one-pass attention into slice s+1
    attn_onepass<<<512, 256, 0, stream>>>(hfeat, bidx, q_star, r_out, z_out);
  }

  final_k<<<128, 256, 0, stream>>>(q_star, r_sl + 5*32768, z_sl + 5*128,
                                   outW, outb, (float*)d_out);
}